// Round 3
// baseline (127.565 us; speedup 1.0000x reference)
//
#include <hip/hip_runtime.h>
#include <cmath>

#define NKEY 3072
#define KSEL 100
#define PCHUNK 128            // preds per k_maxiou block; grid.y = 6400/128 = 50
#define JCHUNK 64             // targets per k_pair block; grid = 100
#define NPAIRBLK 100
#define FB_A 0.5f             // series validity threshold on |a|

static __device__ __forceinline__ float sigf(float v) {
    return 1.0f / (1.0f + expf(-v));
}

// Block (256 threads) sum-reduction in double. Valid result on thread 0.
// Leading barrier makes back-to-back calls safe.
static __device__ double block_reduce_sum(double v) {
    __shared__ double sh[4];
    __syncthreads();
    for (int off = 32; off > 0; off >>= 1) v += __shfl_down(v, off, 64);
    int lane = threadIdx.x & 63, wid = threadIdx.x >> 6;
    if (lane == 0) sh[wid] = v;
    __syncthreads();
    v = (threadIdx.x < 4) ? sh[threadIdx.x] : 0.0;
    if (wid == 0) {
        v += __shfl_down(v, 2, 64);
        v += __shfl_down(v, 1, 64);
    }
    return v;
}

// ---------------------------------------------------------------------------
// k_topk: per-batch (64 blocks) --
//   * build u64 keys (conf_bits<<32 | ~idx), negpen partial
//   * radix-select exact 100th-largest key (top_k tie semantics via packing)
//   * compact + rank + emit pred corners / conf; fix targets; zero maxiou
//   * NEW: reduce S1 = sum (1-conf)^2 and S2 = sum (1-conf)^4 over the
//     selected 100 (feeds k_pair's series-separated closed form)
// ---------------------------------------------------------------------------
__global__ __launch_bounds__(256) void k_topk(const float* __restrict__ pred,
                                              const float* __restrict__ tgt,
                                              float* __restrict__ predc,
                                              float* __restrict__ targc,
                                              float* __restrict__ confv,
                                              unsigned int* __restrict__ maxiou_bits,
                                              double* __restrict__ negp /*[64]*/,
                                              double* __restrict__ S1p /*[64]*/,
                                              double* __restrict__ S2p /*[64]*/) {
    const int b = blockIdx.x;
    const int t = threadIdx.x;

    __shared__ unsigned long long keys[NKEY];   // 24 KB
    __shared__ unsigned int hist[256];
    __shared__ unsigned long long sel[KSEL];
    __shared__ unsigned long long tkey_sh;
    __shared__ unsigned int scnt;
    __shared__ int bdigit_sh;
    __shared__ int bk_sh;

    // ---- target box fixing (epsilon = 1.0) + maxiou init ----
    if (t < KSEL) {
        int n = b * KSEL + t;
        const float* tb = tgt + (size_t)n * 4;
        float a0 = tb[0], a1 = tb[1], a2 = tb[2], a3 = tb[3];
        float x1 = fminf(a0, a2), y1 = fminf(a1, a3);
        float x2 = fmaxf(a0, a2), y2 = fmaxf(a1, a3);
        if (x1 == x2) x2 = x1 + 1.0f;
        if (y1 == y2) y2 = y1 + 1.0f;
        targc[n * 4 + 0] = x1; targc[n * 4 + 1] = y1;
        targc[n * 4 + 2] = x2; targc[n * 4 + 3] = y2;
        maxiou_bits[n] = 0u;
    }
    if (t == 0) scnt = 0;

    // ---- phase A: keys + negpen partial ----
    const float* pb = pred + (size_t)b * (NKEY * 5);
    float negacc = 0.0f;
    for (int r = 0; r < 12; ++r) {
        int idx = t + r * 256;
        const float* pe = pb + (size_t)idx * 5;
        float w = pe[2], h = pe[3], cl = pe[4];
        negacc += fmaxf(1.0f - w, 0.0f) + fmaxf(1.0f - h, 0.0f);
        float c = sigf(cl);
        keys[idx] = ((unsigned long long)__float_as_uint(c) << 32)
                  | (unsigned long long)(0xFFFFFFFFu - (unsigned)idx);
    }
    {
        double v = block_reduce_sum((double)negacc);  // has its own barriers
        if (t == 0) negp[b] = v;
    }
    __syncthreads();  // keys + scnt visible

    // ---- phase B: radix select (MSB-first 8-bit digits) ----
    unsigned long long prefix = 0ull;
    int plen = 0;
    int k = KSEL;
    bool done = false;
    for (int round = 0; round < 8 && !done; ++round) {
        hist[t] = 0u;
        __syncthreads();
        int shift = 56 - 8 * round;
        for (int r = 0; r < 12; ++r) {
            unsigned long long key = keys[t + r * 256];
            if (plen == 0 || (key >> (64 - plen)) == (prefix >> (64 - plen))) {
                atomicAdd(&hist[(unsigned)((key >> shift) & 0xFFull)], 1u);
            }
        }
        __syncthreads();
        if (t < 64) {  // wave 0: suffix-scan the 256-bin histogram
            unsigned s0 = hist[4 * t + 0], s1 = hist[4 * t + 1];
            unsigned s2 = hist[4 * t + 2], s3 = hist[4 * t + 3];
            unsigned ssum = s0 + s1 + s2 + s3;
            unsigned suf = ssum;
            for (int off = 1; off < 64; off <<= 1) {
                unsigned o = __shfl_down(suf, off, 64);
                if (t + off < 64) suf += o;
            }
            unsigned above = suf - ssum;
            if (above < (unsigned)k && suf >= (unsigned)k) {
                unsigned hh[4] = {s0, s1, s2, s3};
                unsigned cum = above;
                for (int q = 3; q >= 0; --q) {
                    unsigned c = hh[q];
                    if (cum + c >= (unsigned)k) { bdigit_sh = 4 * t + q; bk_sh = k - (int)cum; break; }
                    cum += c;
                }
            }
        }
        __syncthreads();
        int d = bdigit_sh;
        k = bk_sh;
        prefix |= ((unsigned long long)(unsigned)d) << shift;
        plen += 8;
        unsigned ceq = hist[d];
        if (ceq == 1u) {
            for (int r = 0; r < 12; ++r) {
                unsigned long long key = keys[t + r * 256];
                if ((key >> (64 - plen)) == (prefix >> (64 - plen))) tkey_sh = key;
            }
            done = true;
        }
        __syncthreads();
    }
    unsigned long long T = tkey_sh;

    // ---- phase C: compact + rank + emit ----
    for (int r = 0; r < 12; ++r) {
        unsigned long long key = keys[t + r * 256];
        if (key >= T) {
            unsigned pos = atomicAdd(&scnt, 1u);  // exactly 100 total
            sel[pos] = key;
        }
    }
    __syncthreads();
    float conf_sel = 0.0f;
    bool have_sel = (t < KSEL);
    if (have_sel) {
        unsigned long long key = sel[t];
        int rank = 0;
        for (int p = 0; p < KSEL; ++p) rank += (sel[p] > key) ? 1 : 0;
        unsigned idx = 0xFFFFFFFFu - (unsigned)(key & 0xFFFFFFFFull);
        float conf = __uint_as_float((unsigned)(key >> 32));
        conf_sel = conf;
        int n = b * KSEL + rank;
        confv[n] = conf;
        const float* pe = pb + (size_t)idx * 5;
        int w = idx & 31, h = (idx >> 5) & 31;  // flat = a*1024 + h*32 + w
        float x  = (sigf(pe[0]) + (float)w) * 32.0f;
        float y  = (sigf(pe[1]) + (float)h) * 32.0f;
        float bw = expf(pe[2]) * 32.0f;
        float bh = expf(pe[3]) * 32.0f;
        predc[n * 4 + 0] = x - bw * 0.5f;
        predc[n * 4 + 1] = y - bh * 0.5f;
        predc[n * 4 + 2] = x + bw * 0.5f;
        predc[n * 4 + 3] = y + bh * 0.5f;
    }
    // ---- S1/S2 partials over this batch's 100 selected confs ----
    double u = 0.0, u2 = 0.0;
    if (have_sel) {
        double d = (double)(1.0f - conf_sel);   // f32 subtract, matches ref
        u = d * d;
        u2 = u * u;
    }
    {
        double s1 = block_reduce_sum(u);
        if (t == 0) S1p[b] = s1;
        double s2 = block_reduce_sum(u2);
        if (t == 0) S2p[b] = s2;
    }
}

// ---------------------------------------------------------------------------
// k_maxiou: grid (25, 50). Division-free running max: maximizing
// in/(S-in) is equivalent under cross-multiplication to "in*bs > bi*S"
// (the in*bi terms cancel), so rcp happens once per thread, not per pair.
// blockIdx.y == 0 additionally computes paired DIoU and the smooth-L1 partial.
// ---------------------------------------------------------------------------
__global__ __launch_bounds__(256) void k_maxiou(const float* __restrict__ predc,
                                                const float* __restrict__ targc,
                                                unsigned int* __restrict__ maxiou_bits,
                                                float* __restrict__ diouv,
                                                double* __restrict__ sl1p /*[25]*/) {
    __shared__ float4 pl[PCHUNK];
    __shared__ float pa_sh[PCHUNK];
    int t = threadIdx.x;
    int j = blockIdx.x * 256 + t;
    const float4* pc4 = (const float4*)predc;
    int i0 = blockIdx.y * PCHUNK;
    if (t < PCHUNK) {
        float4 p = pc4[i0 + t];
        pl[t] = p;
        pa_sh[t] = (p.z - p.x) * (p.w - p.y);
    }
    float4 tj = ((const float4*)targc)[j];
    float ta = (tj.z - tj.x) * (tj.w - tj.y);
    __syncthreads();
    // running best (intersection, pa+ta) pairs; init iou=0 as (0,1)
    float bi0 = 0.f, bs0 = 1.f, bi1 = 0.f, bs1 = 1.f;
    float bi2 = 0.f, bs2 = 1.f, bi3 = 0.f, bs3 = 1.f;
    #pragma unroll 2
    for (int i = 0; i < PCHUNK; i += 4) {
        {
            float4 p = pl[i];
            float w = fmaxf(fminf(p.z, tj.z) - fmaxf(p.x, tj.x), 0.0f);
            float h = fmaxf(fminf(p.w, tj.w) - fmaxf(p.y, tj.y), 0.0f);
            float in = w * h;
            float S = pa_sh[i] + ta;
            bool up = in * bs0 > bi0 * S;
            bi0 = up ? in : bi0; bs0 = up ? S : bs0;
        }
        {
            float4 p = pl[i + 1];
            float w = fmaxf(fminf(p.z, tj.z) - fmaxf(p.x, tj.x), 0.0f);
            float h = fmaxf(fminf(p.w, tj.w) - fmaxf(p.y, tj.y), 0.0f);
            float in = w * h;
            float S = pa_sh[i + 1] + ta;
            bool up = in * bs1 > bi1 * S;
            bi1 = up ? in : bi1; bs1 = up ? S : bs1;
        }
        {
            float4 p = pl[i + 2];
            float w = fmaxf(fminf(p.z, tj.z) - fmaxf(p.x, tj.x), 0.0f);
            float h = fmaxf(fminf(p.w, tj.w) - fmaxf(p.y, tj.y), 0.0f);
            float in = w * h;
            float S = pa_sh[i + 2] + ta;
            bool up = in * bs2 > bi2 * S;
            bi2 = up ? in : bi2; bs2 = up ? S : bs2;
        }
        {
            float4 p = pl[i + 3];
            float w = fmaxf(fminf(p.z, tj.z) - fmaxf(p.x, tj.x), 0.0f);
            float h = fmaxf(fminf(p.w, tj.w) - fmaxf(p.y, tj.y), 0.0f);
            float in = w * h;
            float S = pa_sh[i + 3] + ta;
            bool up = in * bs3 > bi3 * S;
            bi3 = up ? in : bi3; bs3 = up ? S : bs3;
        }
    }
    // merge the 4 chains with the same cross-compare
    {
        bool u01 = bi1 * bs0 > bi0 * bs1;
        float ai = u01 ? bi1 : bi0, as = u01 ? bs1 : bs0;
        bool u23 = bi3 * bs2 > bi2 * bs3;
        float ci = u23 ? bi3 : bi2, cs = u23 ? bs3 : bs2;
        bool um = ci * as > ai * cs;
        float fi = um ? ci : ai, fs = um ? cs : as;
        float iou = fi * __builtin_amdgcn_rcpf(fs - fi);  // union > 0 (or 1 at init)
        atomicMax(&maxiou_bits[j], __float_as_uint(iou));
    }

    if (blockIdx.y == 0) {
        float4 p = pc4[j];  // paired pred for target j
        float pa = fmaxf(p.z - p.x, 0.f) * fmaxf(p.w - p.y, 0.f);
        float ta2 = fmaxf(tj.z - tj.x, 0.f) * fmaxf(tj.w - tj.y, 0.f);
        float ix1 = fmaxf(p.x, tj.x), iy1 = fmaxf(p.y, tj.y);
        float ix2 = fminf(p.z, tj.z), iy2 = fminf(p.w, tj.w);
        float inter = fmaxf(ix2 - ix1, 0.f) * fmaxf(iy2 - iy1, 0.f);
        float iou = inter / (pa + ta2 - inter + 1e-7f);
        float pcx = (p.x + p.z) * 0.5f, pcy = (p.y + p.w) * 0.5f;
        float tcx = (tj.x + tj.z) * 0.5f, tcy = (tj.y + tj.w) * 0.5f;
        float cd = (pcx - tcx) * (pcx - tcx) + (pcy - tcy) * (pcy - tcy);
        float ex1 = fminf(p.x, tj.x), ey1 = fminf(p.y, tj.y);
        float ex2 = fmaxf(p.z, tj.z), ey2 = fmaxf(p.w, tj.w);
        float dg = (ex2 - ex1) * (ex2 - ex1) + (ey2 - ey1) * (ey2 - ey1);
        diouv[j] = 1.0f - (iou - cd / (dg + 1e-7f));
        double s = 0.0;
        {
            float d0 = p.x - tj.x, d1 = p.y - tj.y, d2 = p.z - tj.z, d3 = p.w - tj.w;
            float a0 = fabsf(d0), a1 = fabsf(d1), a2 = fabsf(d2), a3 = fabsf(d3);
            s += (double)(a0 < 1.f ? 0.5f * d0 * d0 : a0 - 0.5f);
            s += (double)(a1 < 1.f ? 0.5f * d1 * d1 : a1 - 0.5f);
            s += (double)(a2 < 1.f ? 0.5f * d2 * d2 : a2 - 0.5f);
            s += (double)(a3 < 1.f ? 0.5f * d3 * d3 : a3 - 0.5f);
        }
        double v = block_reduce_sum(s);
        if (t == 0) sl1p[blockIdx.x] = v;
    }
}

// ---------------------------------------------------------------------------
// k_pair: series-separated O(N) version. For each j:
//   sum_i sqrt(a^2 + u_i)  ~=  6400*a + S1/(2a) - S2/(8a^3),  u_i=(1-conf_i)^2
// valid to <= u^3/(16 a^5) ~ 2.3e-5/pair for |a| >= 0.5 (u <= ~0.024 since
// conf are top-100 sigmoids >= ~0.85). j's with |a| < 0.5 go to an exact
// wave-parallel fallback over all 6400 i (compacted LDS worklist).
// Grid: 100 blocks x 256; each block owns 64 j's; partial -> pairp[100].
// ---------------------------------------------------------------------------
__global__ __launch_bounds__(256) void k_pair(const unsigned int* __restrict__ maxiou_bits,
                                              const float* __restrict__ diouv,
                                              const float* __restrict__ confv,
                                              const double* __restrict__ sl1p /*[25]*/,
                                              const double* __restrict__ S1p  /*[64]*/,
                                              const double* __restrict__ S2p  /*[64]*/,
                                              double* __restrict__ pairp /*[100]*/) {
    __shared__ float xval[JCHUNK];
    __shared__ int flist[2 * JCHUNK];
    __shared__ unsigned int fcnt;
    __shared__ double fw[4];
    int t = threadIdx.x;
    int wid = t >> 6, lane = t & 63;
    if (t == 0) fcnt = 0;

    // every wave computes the global scalars (redundant, avoids broadcast)
    double S1, S2;
    float sl1;
    {
        double a = (lane < 25) ? sl1p[lane] : 0.0;
        for (int off = 32; off; off >>= 1) a += __shfl_xor(a, off, 64);
        sl1 = (float)(a / 25600.0 / 512.0);
        double b = S1p[lane];
        for (int off = 32; off; off >>= 1) b += __shfl_xor(b, off, 64);
        S1 = b;
        double c = S2p[lane];
        for (int off = 32; off; off >>= 1) c += __shfl_xor(c, off, 64);
        S2 = c;
    }

    double v = 0.0;
    if (t < JCHUNK) {   // wave 0: closed form per j (+ fallback detection)
        int j = blockIdx.x * JCHUNK + t;
        float mj = __uint_as_float(maxiou_bits[j]);
        float dj = diouv[j];
        float xj = (1.0f - mj) * 2.0f + dj + sl1;
        xval[t] = xj;
        double X = (double)xj;
        double AB = fabs(3.5 - X);
        double c = 0.0;
        if (xj >= FB_A) {
            c += 2.0 * (6400.0 * X + S1 / (2.0 * X) - S2 / (8.0 * X * X * X));
        } else {
            unsigned p = atomicAdd(&fcnt, 1u);
            flist[p] = (t << 1);
        }
        if (AB >= (double)FB_A) {
            c -= 1.5 * (6400.0 * AB + S1 / (2.0 * AB) - S2 / (8.0 * AB * AB * AB));
        } else {
            unsigned p = atomicAdd(&fcnt, 1u);
            flist[p] = (t << 1) | 1;
        }
        v = c;
    }
    __syncthreads();
    // exact fallback: waves round-robin worklist entries, i-parallel
    int nf = (int)fcnt;
    double facc = 0.0;
    for (int e = wid; e < nf; e += 4) {
        int ent = flist[e];
        int jl = ent >> 1, side = ent & 1;
        float xj = xval[jl];
        float a = side ? fabsf(3.5f - xj) : xj;
        float a2 = a * a;
        float acc = 0.0f;
        for (int it = 0; it < 100; ++it) {
            float cf = confv[it * 64 + lane];
            float o = 1.0f - cf;
            acc += __builtin_amdgcn_sqrtf(fmaf(o, o, a2));
        }
        for (int off = 32; off; off >>= 1) acc += __shfl_xor(acc, off, 64);
        facc += side ? -1.5 * (double)acc : 2.0 * (double)acc;
    }
    if (lane == 0) fw[wid] = facc;
    __syncthreads();
    if (t < 4) v += fw[t];
    double r = block_reduce_sum(v);
    if (t == 0) pairp[blockIdx.x] = r;
}

// ---------------------------------------------------------------------------
// k_final: reduce 100 pair partials + 64 negpen partials, emit scalar.
// ---------------------------------------------------------------------------
__global__ __launch_bounds__(256) void k_final(const double* __restrict__ pairp,
                                               const double* __restrict__ negp,
                                               float* __restrict__ out) {
    int t = threadIdx.x;
    double s = (t < NPAIRBLK) ? pairp[t] : 0.0;
    double ps = block_reduce_sum(s);
    double n = (t < 64) ? negp[t] : 0.0;
    double ns = block_reduce_sum(n);
    if (t == 0) {
        double mean_pair = ps / 40960000.0;                    // 6400*6400
        float losses = fmaxf((float)mean_pair + 5.25f, 0.0f);  // + 3.5*1.5
        float neg = (float)(ns / 196608.0);
        out[0] = losses + neg;
    }
}

// ---------------- launch ----------------

extern "C" void kernel_launch(void* const* d_in, const int* in_sizes, int n_in,
                              void* d_out, int out_size, void* d_ws, size_t ws_size,
                              hipStream_t stream) {
    const float* pred = (const float*)d_in[0];   // [64,3,32,32,5]
    const float* tgt  = (const float*)d_in[1];   // [64,100,4]
    float* out = (float*)d_out;

    char* ws = (char*)d_ws;
    double* negp  = (double*)ws;             // 64 doubles
    double* sl1p  = negp + 64;               // 25 (pad to 32)
    double* S1p   = negp + 96;               // 64
    double* S2p   = negp + 160;              // 64
    double* pairp = negp + 224;              // 100 -> ends at 324*8 = 2592
    float* fbase  = (float*)(ws + 2592);     // 16B-aligned float region
    float* predc  = fbase;                   // 25600 floats
    float* targc  = fbase + 25600;           // 25600
    float* confv  = fbase + 51200;           // 6400
    float* diouv  = fbase + 57600;           // 6400
    unsigned int* maxiou_bits = (unsigned int*)(fbase + 64000);  // 6400

    k_topk<<<64, 256, 0, stream>>>(pred, tgt, predc, targc, confv, maxiou_bits,
                                   negp, S1p, S2p);
    k_maxiou<<<dim3(25, 6400 / PCHUNK), 256, 0, stream>>>(predc, targc, maxiou_bits,
                                                          diouv, sl1p);
    k_pair<<<NPAIRBLK, 256, 0, stream>>>(maxiou_bits, diouv, confv, sl1p, S1p, S2p, pairp);
    k_final<<<1, 256, 0, stream>>>(pairp, negp, out);
}

// Round 4
// 100.154 us; speedup vs baseline: 1.2737x; 1.2737x over previous
//
#include <hip/hip_runtime.h>
#include <cmath>

#define NKEY 3072
#define KSEL 100
#define PCHUNK 128            // preds per k_maxiou block; grid.y = 6400/128 = 50
#define ICHUNK 128            // confs per k_pair block;  grid.y = 50
#define NPAIRBLK (25 * 50)    // 1250 pair partials
#define GOOD_MIN 0.5f         // good-side series valid for x >= 0.5 (err <= 6e-7/pair)

static __device__ __forceinline__ float sigf(float v) {
    return 1.0f / (1.0f + expf(-v));
}

// Block (256 threads) sum-reduction in double. Valid result on thread 0.
// Leading barrier makes back-to-back calls safe.
static __device__ double block_reduce_sum(double v) {
    __shared__ double sh[4];
    __syncthreads();
    for (int off = 32; off > 0; off >>= 1) v += __shfl_down(v, off, 64);
    int lane = threadIdx.x & 63, wid = threadIdx.x >> 6;
    if (lane == 0) sh[wid] = v;
    __syncthreads();
    v = (threadIdx.x < 4) ? sh[threadIdx.x] : 0.0;
    if (wid == 0) {
        v += __shfl_down(v, 2, 64);
        v += __shfl_down(v, 1, 64);
    }
    return v;
}

// ---------------------------------------------------------------------------
// k_topk: per-batch (64 blocks) --
//   * build u64 keys (conf_bits<<32 | ~idx), negpen partial
//   * radix-select exact 100th-largest key (top_k tie semantics via packing)
//   * compact + rank + emit pred corners / conf; fix targets; zero maxiou
//   * S1/S2/S3 partials: sum (1-conf)^{2,4,6} over the selected 100
//     (feeds k_pair's good-side closed form)
// ---------------------------------------------------------------------------
__global__ __launch_bounds__(256) void k_topk(const float* __restrict__ pred,
                                              const float* __restrict__ tgt,
                                              float* __restrict__ predc,
                                              float* __restrict__ targc,
                                              float* __restrict__ confv,
                                              unsigned int* __restrict__ maxiou_bits,
                                              double* __restrict__ negp /*[64]*/,
                                              double* __restrict__ S1p /*[64]*/,
                                              double* __restrict__ S2p /*[64]*/,
                                              double* __restrict__ S3p /*[64]*/) {
    const int b = blockIdx.x;
    const int t = threadIdx.x;

    __shared__ unsigned long long keys[NKEY];   // 24 KB
    __shared__ unsigned int hist[256];
    __shared__ unsigned long long sel[KSEL];
    __shared__ unsigned long long tkey_sh;
    __shared__ unsigned int scnt;
    __shared__ int bdigit_sh;
    __shared__ int bk_sh;

    // ---- target box fixing (epsilon = 1.0) + maxiou init ----
    if (t < KSEL) {
        int n = b * KSEL + t;
        const float* tb = tgt + (size_t)n * 4;
        float a0 = tb[0], a1 = tb[1], a2 = tb[2], a3 = tb[3];
        float x1 = fminf(a0, a2), y1 = fminf(a1, a3);
        float x2 = fmaxf(a0, a2), y2 = fmaxf(a1, a3);
        if (x1 == x2) x2 = x1 + 1.0f;
        if (y1 == y2) y2 = y1 + 1.0f;
        targc[n * 4 + 0] = x1; targc[n * 4 + 1] = y1;
        targc[n * 4 + 2] = x2; targc[n * 4 + 3] = y2;
        maxiou_bits[n] = 0u;
    }
    if (t == 0) scnt = 0;

    // ---- phase A: keys + negpen partial ----
    const float* pb = pred + (size_t)b * (NKEY * 5);
    float negacc = 0.0f;
    for (int r = 0; r < 12; ++r) {
        int idx = t + r * 256;
        const float* pe = pb + (size_t)idx * 5;
        float w = pe[2], h = pe[3], cl = pe[4];
        negacc += fmaxf(1.0f - w, 0.0f) + fmaxf(1.0f - h, 0.0f);
        float c = sigf(cl);
        keys[idx] = ((unsigned long long)__float_as_uint(c) << 32)
                  | (unsigned long long)(0xFFFFFFFFu - (unsigned)idx);
    }
    {
        double v = block_reduce_sum((double)negacc);  // has its own barriers
        if (t == 0) negp[b] = v;
    }
    __syncthreads();  // keys + scnt visible

    // ---- phase B: radix select (MSB-first 8-bit digits) ----
    unsigned long long prefix = 0ull;
    int plen = 0;
    int k = KSEL;
    bool done = false;
    for (int round = 0; round < 8 && !done; ++round) {
        hist[t] = 0u;
        __syncthreads();
        int shift = 56 - 8 * round;
        for (int r = 0; r < 12; ++r) {
            unsigned long long key = keys[t + r * 256];
            if (plen == 0 || (key >> (64 - plen)) == (prefix >> (64 - plen))) {
                atomicAdd(&hist[(unsigned)((key >> shift) & 0xFFull)], 1u);
            }
        }
        __syncthreads();
        if (t < 64) {  // wave 0: suffix-scan the 256-bin histogram
            unsigned s0 = hist[4 * t + 0], s1 = hist[4 * t + 1];
            unsigned s2 = hist[4 * t + 2], s3 = hist[4 * t + 3];
            unsigned ssum = s0 + s1 + s2 + s3;
            unsigned suf = ssum;
            for (int off = 1; off < 64; off <<= 1) {
                unsigned o = __shfl_down(suf, off, 64);
                if (t + off < 64) suf += o;
            }
            unsigned above = suf - ssum;
            if (above < (unsigned)k && suf >= (unsigned)k) {
                unsigned hh[4] = {s0, s1, s2, s3};
                unsigned cum = above;
                for (int q = 3; q >= 0; --q) {
                    unsigned c = hh[q];
                    if (cum + c >= (unsigned)k) { bdigit_sh = 4 * t + q; bk_sh = k - (int)cum; break; }
                    cum += c;
                }
            }
        }
        __syncthreads();
        int d = bdigit_sh;
        k = bk_sh;
        prefix |= ((unsigned long long)(unsigned)d) << shift;
        plen += 8;
        unsigned ceq = hist[d];
        if (ceq == 1u) {
            for (int r = 0; r < 12; ++r) {
                unsigned long long key = keys[t + r * 256];
                if ((key >> (64 - plen)) == (prefix >> (64 - plen))) tkey_sh = key;
            }
            done = true;
        }
        __syncthreads();
    }
    unsigned long long T = tkey_sh;

    // ---- phase C: compact + rank + emit ----
    for (int r = 0; r < 12; ++r) {
        unsigned long long key = keys[t + r * 256];
        if (key >= T) {
            unsigned pos = atomicAdd(&scnt, 1u);  // exactly 100 total
            sel[pos] = key;
        }
    }
    __syncthreads();
    float conf_sel = 0.0f;
    bool have_sel = (t < KSEL);
    if (have_sel) {
        unsigned long long key = sel[t];
        int rank = 0;
        for (int p = 0; p < KSEL; ++p) rank += (sel[p] > key) ? 1 : 0;
        unsigned idx = 0xFFFFFFFFu - (unsigned)(key & 0xFFFFFFFFull);
        float conf = __uint_as_float((unsigned)(key >> 32));
        conf_sel = conf;
        int n = b * KSEL + rank;
        confv[n] = conf;
        const float* pe = pb + (size_t)idx * 5;
        int w = idx & 31, h = (idx >> 5) & 31;  // flat = a*1024 + h*32 + w
        float x  = (sigf(pe[0]) + (float)w) * 32.0f;
        float y  = (sigf(pe[1]) + (float)h) * 32.0f;
        float bw = expf(pe[2]) * 32.0f;
        float bh = expf(pe[3]) * 32.0f;
        predc[n * 4 + 0] = x - bw * 0.5f;
        predc[n * 4 + 1] = y - bh * 0.5f;
        predc[n * 4 + 2] = x + bw * 0.5f;
        predc[n * 4 + 3] = y + bh * 0.5f;
    }
    // ---- S1/S2/S3 partials over this batch's 100 selected confs ----
    double u = 0.0, u2 = 0.0, u3 = 0.0;
    if (have_sel) {
        double d = (double)(1.0f - conf_sel);   // f32 subtract, matches ref
        u = d * d;
        u2 = u * u;
        u3 = u2 * u;
    }
    {
        double s1 = block_reduce_sum(u);
        if (t == 0) S1p[b] = s1;
        double s2 = block_reduce_sum(u2);
        if (t == 0) S2p[b] = s2;
        double s3 = block_reduce_sum(u3);
        if (t == 0) S3p[b] = s3;
    }
}

// ---------------------------------------------------------------------------
// k_maxiou: grid (25, 50). Division-free running max (validated round 3):
// maximizing in/(S-in) == cross-compare "in*bs > bi*S" (in*bi terms cancel);
// rcp once per thread at the end.
// blockIdx.y == 0 additionally computes paired DIoU and the smooth-L1 partial.
// ---------------------------------------------------------------------------
__global__ __launch_bounds__(256) void k_maxiou(const float* __restrict__ predc,
                                                const float* __restrict__ targc,
                                                unsigned int* __restrict__ maxiou_bits,
                                                float* __restrict__ diouv,
                                                double* __restrict__ sl1p /*[25]*/) {
    __shared__ float4 pl[PCHUNK];
    __shared__ float pa_sh[PCHUNK];
    int t = threadIdx.x;
    int j = blockIdx.x * 256 + t;
    const float4* pc4 = (const float4*)predc;
    int i0 = blockIdx.y * PCHUNK;
    if (t < PCHUNK) {
        float4 p = pc4[i0 + t];
        pl[t] = p;
        pa_sh[t] = (p.z - p.x) * (p.w - p.y);
    }
    float4 tj = ((const float4*)targc)[j];
    float ta = (tj.z - tj.x) * (tj.w - tj.y);
    __syncthreads();
    // running best (intersection, pa+ta) pairs; init iou=0 as (0,1)
    float bi0 = 0.f, bs0 = 1.f, bi1 = 0.f, bs1 = 1.f;
    float bi2 = 0.f, bs2 = 1.f, bi3 = 0.f, bs3 = 1.f;
    #pragma unroll 2
    for (int i = 0; i < PCHUNK; i += 4) {
        {
            float4 p = pl[i];
            float w = fmaxf(fminf(p.z, tj.z) - fmaxf(p.x, tj.x), 0.0f);
            float h = fmaxf(fminf(p.w, tj.w) - fmaxf(p.y, tj.y), 0.0f);
            float in = w * h;
            float S = pa_sh[i] + ta;
            bool up = in * bs0 > bi0 * S;
            bi0 = up ? in : bi0; bs0 = up ? S : bs0;
        }
        {
            float4 p = pl[i + 1];
            float w = fmaxf(fminf(p.z, tj.z) - fmaxf(p.x, tj.x), 0.0f);
            float h = fmaxf(fminf(p.w, tj.w) - fmaxf(p.y, tj.y), 0.0f);
            float in = w * h;
            float S = pa_sh[i + 1] + ta;
            bool up = in * bs1 > bi1 * S;
            bi1 = up ? in : bi1; bs1 = up ? S : bs1;
        }
        {
            float4 p = pl[i + 2];
            float w = fmaxf(fminf(p.z, tj.z) - fmaxf(p.x, tj.x), 0.0f);
            float h = fmaxf(fminf(p.w, tj.w) - fmaxf(p.y, tj.y), 0.0f);
            float in = w * h;
            float S = pa_sh[i + 2] + ta;
            bool up = in * bs2 > bi2 * S;
            bi2 = up ? in : bi2; bs2 = up ? S : bs2;
        }
        {
            float4 p = pl[i + 3];
            float w = fmaxf(fminf(p.z, tj.z) - fmaxf(p.x, tj.x), 0.0f);
            float h = fmaxf(fminf(p.w, tj.w) - fmaxf(p.y, tj.y), 0.0f);
            float in = w * h;
            float S = pa_sh[i + 3] + ta;
            bool up = in * bs3 > bi3 * S;
            bi3 = up ? in : bi3; bs3 = up ? S : bs3;
        }
    }
    {
        bool u01 = bi1 * bs0 > bi0 * bs1;
        float ai = u01 ? bi1 : bi0, as = u01 ? bs1 : bs0;
        bool u23 = bi3 * bs2 > bi2 * bs3;
        float ci = u23 ? bi3 : bi2, cs = u23 ? bs3 : bs2;
        bool um = ci * as > ai * cs;
        float fi = um ? ci : ai, fs = um ? cs : as;
        float iou = fi * __builtin_amdgcn_rcpf(fs - fi);  // union > 0 (or 1 at init)
        atomicMax(&maxiou_bits[j], __float_as_uint(iou));
    }

    if (blockIdx.y == 0) {
        float4 p = pc4[j];  // paired pred for target j
        float pa = fmaxf(p.z - p.x, 0.f) * fmaxf(p.w - p.y, 0.f);
        float ta2 = fmaxf(tj.z - tj.x, 0.f) * fmaxf(tj.w - tj.y, 0.f);
        float ix1 = fmaxf(p.x, tj.x), iy1 = fmaxf(p.y, tj.y);
        float ix2 = fminf(p.z, tj.z), iy2 = fminf(p.w, tj.w);
        float inter = fmaxf(ix2 - ix1, 0.f) * fmaxf(iy2 - iy1, 0.f);
        float iou = inter / (pa + ta2 - inter + 1e-7f);
        float pcx = (p.x + p.z) * 0.5f, pcy = (p.y + p.w) * 0.5f;
        float tcx = (tj.x + tj.z) * 0.5f, tcy = (tj.y + tj.w) * 0.5f;
        float cd = (pcx - tcx) * (pcx - tcx) + (pcy - tcy) * (pcy - tcy);
        float ex1 = fminf(p.x, tj.x), ey1 = fminf(p.y, tj.y);
        float ex2 = fmaxf(p.z, tj.z), ey2 = fmaxf(p.w, tj.w);
        float dg = (ex2 - ex1) * (ex2 - ex1) + (ey2 - ey1) * (ey2 - ey1);
        diouv[j] = 1.0f - (iou - cd / (dg + 1e-7f));
        double s = 0.0;
        {
            float d0 = p.x - tj.x, d1 = p.y - tj.y, d2 = p.z - tj.z, d3 = p.w - tj.w;
            float a0 = fabsf(d0), a1 = fabsf(d1), a2 = fabsf(d2), a3 = fabsf(d3);
            s += (double)(a0 < 1.f ? 0.5f * d0 * d0 : a0 - 0.5f);
            s += (double)(a1 < 1.f ? 0.5f * d1 * d1 : a1 - 0.5f);
            s += (double)(a2 < 1.f ? 0.5f * d2 * d2 : a2 - 0.5f);
            s += (double)(a3 < 1.f ? 0.5f * d3 * d3 : a3 - 0.5f);
        }
        double v = block_reduce_sum(s);
        if (t == 0) sl1p[blockIdx.x] = v;
    }
}

// ---------------------------------------------------------------------------
// k_pair: asymmetric split. Per pair (j,i):
//   bad  = 1.5*sqrt((3.5-x_j)^2 + u_i)  -- EXACT always (x_j clusters at 3.5,
//          the series singularity; measured round 3)
//   good = 2.0*sqrt(x_j^2 + u_i)        -- closed form: x_j >= 0.5 holds in
//          practice (x_j ~ 3.3); series sum = 6400*X + S1/(2X) - S2/(8X^3)
//          + S3/(16X^5), err <= 6e-7/pair at X=0.5. Rare x_j < 0.5 -> exact
//          in the same loop (predicated).
// Grid (25, 50) as round-2 exact; inner loop now ONE sqrt instead of two.
// blockIdx.y == 0 threads additionally emit the good-side closed form.
// ---------------------------------------------------------------------------
__global__ __launch_bounds__(256) void k_pair(const unsigned int* __restrict__ maxiou_bits,
                                              const float* __restrict__ diouv,
                                              const float* __restrict__ confv,
                                              const double* __restrict__ sl1p /*[25]*/,
                                              const double* __restrict__ S1p  /*[64]*/,
                                              const double* __restrict__ S2p  /*[64]*/,
                                              const double* __restrict__ S3p  /*[64]*/,
                                              double* __restrict__ pairp /*[1250]*/) {
    __shared__ float uch[ICHUNK];
    int t = threadIdx.x;
    int lane = t & 63;
    int j = blockIdx.x * 256 + t;

    // per-wave global scalars (sl1 needed by all; S1..S3 only used by y==0)
    float sl1;
    {
        double a = (lane < 25) ? sl1p[lane] : 0.0;
        for (int off = 32; off; off >>= 1) a += __shfl_xor(a, off, 64);
        sl1 = (float)(a / 25600.0 / 512.0);
    }
    if (t < ICHUNK) {
        float cf = confv[blockIdx.y * ICHUNK + t];
        float o = 1.0f - cf;
        uch[t] = o * o;
    }
    float mj = __uint_as_float(maxiou_bits[j]);
    float dj = diouv[j];
    __syncthreads();
    float xj = (1.0f - mj) * 2.0f + dj + sl1;
    float bb = 3.5f - xj;
    float b2 = bb * bb;
    float x2 = xj * xj;
    bool gexact = (xj < GOOD_MIN);

    float bacc0 = 0.0f, bacc1 = 0.0f;
    float gacc = 0.0f;
    if (!gexact) {
        #pragma unroll 4
        for (int i = 0; i < ICHUNK; i += 2) {
            float u0 = uch[i], u1 = uch[i + 1];
            bacc0 += __builtin_amdgcn_sqrtf(b2 + u0);
            bacc1 += __builtin_amdgcn_sqrtf(b2 + u1);
        }
    } else {
        #pragma unroll 2
        for (int i = 0; i < ICHUNK; i += 2) {
            float u0 = uch[i], u1 = uch[i + 1];
            bacc0 += __builtin_amdgcn_sqrtf(b2 + u0);
            bacc1 += __builtin_amdgcn_sqrtf(b2 + u1);
            gacc  += __builtin_amdgcn_sqrtf(x2 + u0)
                   + __builtin_amdgcn_sqrtf(x2 + u1);
        }
    }
    double v = -1.5 * (double)(bacc0 + bacc1) + 2.0 * (double)gacc;

    if (blockIdx.y == 0 && !gexact) {
        // good-side closed form over ALL 6400 i (once per j, done by y==0)
        double S1, S2, S3;
        {
            double b = S1p[lane];
            for (int off = 32; off; off >>= 1) b += __shfl_xor(b, off, 64);
            S1 = b;
            double c = S2p[lane];
            for (int off = 32; off; off >>= 1) c += __shfl_xor(c, off, 64);
            S2 = c;
            double d = S3p[lane];
            for (int off = 32; off; off >>= 1) d += __shfl_xor(d, off, 64);
            S3 = d;
        }
        double X = (double)xj;
        double iX = 1.0 / X, iX2 = iX * iX;
        v += 2.0 * (6400.0 * X + 0.5 * S1 * iX - 0.125 * S2 * iX * iX2
                    + 0.0625 * S3 * iX * iX2 * iX2);
    }
    double r = block_reduce_sum(v);
    if (t == 0) pairp[blockIdx.x * 50 + blockIdx.y] = r;
}

// ---------------------------------------------------------------------------
// k_final: reduce 1250 pair partials + 64 negpen partials, emit scalar.
// ---------------------------------------------------------------------------
__global__ __launch_bounds__(256) void k_final(const double* __restrict__ pairp,
                                               const double* __restrict__ negp,
                                               float* __restrict__ out) {
    int t = threadIdx.x;
    double s = 0.0;
    for (int i = t; i < NPAIRBLK; i += 256) s += pairp[i];
    double ps = block_reduce_sum(s);
    double n = (t < 64) ? negp[t] : 0.0;
    double ns = block_reduce_sum(n);
    if (t == 0) {
        double mean_pair = ps / 40960000.0;                    // 6400*6400
        float losses = fmaxf((float)mean_pair + 5.25f, 0.0f);  // + 3.5*1.5
        float neg = (float)(ns / 196608.0);
        out[0] = losses + neg;
    }
}

// ---------------- launch ----------------

extern "C" void kernel_launch(void* const* d_in, const int* in_sizes, int n_in,
                              void* d_out, int out_size, void* d_ws, size_t ws_size,
                              hipStream_t stream) {
    const float* pred = (const float*)d_in[0];   // [64,3,32,32,5]
    const float* tgt  = (const float*)d_in[1];   // [64,100,4]
    float* out = (float*)d_out;

    char* ws = (char*)d_ws;
    double* negp  = (double*)ws;             // 64 doubles
    double* sl1p  = negp + 64;               // 25 (pad to 32)
    double* S1p   = negp + 96;               // 64
    double* S2p   = negp + 160;              // 64
    double* S3p   = negp + 224;              // 64
    double* pairp = negp + 288;              // 1250 -> ends at 1538*8 = 12304
    float* fbase  = (float*)(ws + 12304);    // 16B-aligned float region
    float* predc  = fbase;                   // 25600 floats
    float* targc  = fbase + 25600;           // 25600
    float* confv  = fbase + 51200;           // 6400
    float* diouv  = fbase + 57600;           // 6400
    unsigned int* maxiou_bits = (unsigned int*)(fbase + 64000);  // 6400

    k_topk<<<64, 256, 0, stream>>>(pred, tgt, predc, targc, confv, maxiou_bits,
                                   negp, S1p, S2p, S3p);
    k_maxiou<<<dim3(25, 6400 / PCHUNK), 256, 0, stream>>>(predc, targc, maxiou_bits,
                                                          diouv, sl1p);
    k_pair<<<dim3(25, 6400 / ICHUNK), 256, 0, stream>>>(maxiou_bits, diouv, confv,
                                                        sl1p, S1p, S2p, S3p, pairp);
    k_final<<<1, 256, 0, stream>>>(pairp, negp, out);
}

// Round 5
// 96.169 us; speedup vs baseline: 1.3265x; 1.0414x over previous
//
#include <hip/hip_runtime.h>
#include <cmath>

#define NKEY 3072
#define KSEL 100
#define PCHUNK 128            // preds per k_maxiou block; grid.y = 6400/128 = 50
#define HBUCK 128             // u-histogram buckets over u in [0, 0.0625)
#define HSCALE 2048.0f        // HBUCK / 0.0625
#define HSLICE 32             // buckets per k_pair y-block; grid.y = 4
#define NPAIRBLK (25 * 4)     // 100 pair partials

static __device__ __forceinline__ float sigf(float v) {
    return 1.0f / (1.0f + expf(-v));
}

// Block (256 threads) sum-reduction in double. Valid result on thread 0.
// Leading barrier makes back-to-back calls safe.
static __device__ double block_reduce_sum(double v) {
    __shared__ double sh[4];
    __syncthreads();
    for (int off = 32; off > 0; off >>= 1) v += __shfl_down(v, off, 64);
    int lane = threadIdx.x & 63, wid = threadIdx.x >> 6;
    if (lane == 0) sh[wid] = v;
    __syncthreads();
    v = (threadIdx.x < 4) ? sh[threadIdx.x] : 0.0;
    if (wid == 0) {
        v += __shfl_down(v, 2, 64);
        v += __shfl_down(v, 1, 64);
    }
    return v;
}

// ---------------------------------------------------------------------------
// k_topk: per-batch (64 blocks) --
//   * build u64 keys (conf_bits<<32 | ~idx), negpen partial
//   * radix-select exact 100th-largest key (top_k tie semantics via packing)
//   * compact + rank + emit pred corners; fix targets; zero maxiou
//   * u-histogram: bucket u = (1-conf)^2 of the 100 selected confs into
//     128 buckets (cnt, sum_u) -> hist_g[2][128][64]; replaces per-pair
//     conf reads in k_pair entirely.
// ---------------------------------------------------------------------------
__global__ __launch_bounds__(256) void k_topk(const float* __restrict__ pred,
                                              const float* __restrict__ tgt,
                                              float* __restrict__ predc,
                                              float* __restrict__ targc,
                                              unsigned int* __restrict__ maxiou_bits,
                                              double* __restrict__ negp /*[64]*/,
                                              float* __restrict__ hist_g /*[2][128][64]*/) {
    const int b = blockIdx.x;
    const int t = threadIdx.x;

    __shared__ unsigned long long keys[NKEY];   // 24 KB
    __shared__ unsigned int hist[256];
    __shared__ unsigned long long sel[KSEL];
    __shared__ unsigned long long tkey_sh;
    __shared__ unsigned int scnt;
    __shared__ int bdigit_sh;
    __shared__ int bk_sh;
    __shared__ float hcnt[HBUCK];
    __shared__ float hsum[HBUCK];

    // ---- target box fixing (epsilon = 1.0) + maxiou init ----
    if (t < KSEL) {
        int n = b * KSEL + t;
        const float* tb = tgt + (size_t)n * 4;
        float a0 = tb[0], a1 = tb[1], a2 = tb[2], a3 = tb[3];
        float x1 = fminf(a0, a2), y1 = fminf(a1, a3);
        float x2 = fmaxf(a0, a2), y2 = fmaxf(a1, a3);
        if (x1 == x2) x2 = x1 + 1.0f;
        if (y1 == y2) y2 = y1 + 1.0f;
        targc[n * 4 + 0] = x1; targc[n * 4 + 1] = y1;
        targc[n * 4 + 2] = x2; targc[n * 4 + 3] = y2;
        maxiou_bits[n] = 0u;
    }
    if (t == 0) scnt = 0;
    if (t < HBUCK) { hcnt[t] = 0.0f; hsum[t] = 0.0f; }

    // ---- phase A: keys + negpen partial ----
    const float* pb = pred + (size_t)b * (NKEY * 5);
    float negacc = 0.0f;
    for (int r = 0; r < 12; ++r) {
        int idx = t + r * 256;
        const float* pe = pb + (size_t)idx * 5;
        float w = pe[2], h = pe[3], cl = pe[4];
        negacc += fmaxf(1.0f - w, 0.0f) + fmaxf(1.0f - h, 0.0f);
        float c = sigf(cl);
        keys[idx] = ((unsigned long long)__float_as_uint(c) << 32)
                  | (unsigned long long)(0xFFFFFFFFu - (unsigned)idx);
    }
    {
        double v = block_reduce_sum((double)negacc);  // has its own barriers
        if (t == 0) negp[b] = v;
    }
    __syncthreads();  // keys + scnt + hcnt/hsum visible

    // ---- phase B: radix select (MSB-first 8-bit digits) ----
    unsigned long long prefix = 0ull;
    int plen = 0;
    int k = KSEL;
    bool done = false;
    for (int round = 0; round < 8 && !done; ++round) {
        hist[t] = 0u;
        __syncthreads();
        int shift = 56 - 8 * round;
        for (int r = 0; r < 12; ++r) {
            unsigned long long key = keys[t + r * 256];
            if (plen == 0 || (key >> (64 - plen)) == (prefix >> (64 - plen))) {
                atomicAdd(&hist[(unsigned)((key >> shift) & 0xFFull)], 1u);
            }
        }
        __syncthreads();
        if (t < 64) {  // wave 0: suffix-scan the 256-bin histogram
            unsigned s0 = hist[4 * t + 0], s1 = hist[4 * t + 1];
            unsigned s2 = hist[4 * t + 2], s3 = hist[4 * t + 3];
            unsigned ssum = s0 + s1 + s2 + s3;
            unsigned suf = ssum;
            for (int off = 1; off < 64; off <<= 1) {
                unsigned o = __shfl_down(suf, off, 64);
                if (t + off < 64) suf += o;
            }
            unsigned above = suf - ssum;
            if (above < (unsigned)k && suf >= (unsigned)k) {
                unsigned hh[4] = {s0, s1, s2, s3};
                unsigned cum = above;
                for (int q = 3; q >= 0; --q) {
                    unsigned c = hh[q];
                    if (cum + c >= (unsigned)k) { bdigit_sh = 4 * t + q; bk_sh = k - (int)cum; break; }
                    cum += c;
                }
            }
        }
        __syncthreads();
        int d = bdigit_sh;
        k = bk_sh;
        prefix |= ((unsigned long long)(unsigned)d) << shift;
        plen += 8;
        unsigned ceq = hist[d];
        if (ceq == 1u) {
            for (int r = 0; r < 12; ++r) {
                unsigned long long key = keys[t + r * 256];
                if ((key >> (64 - plen)) == (prefix >> (64 - plen))) tkey_sh = key;
            }
            done = true;
        }
        __syncthreads();
    }
    unsigned long long T = tkey_sh;

    // ---- phase C: compact + rank + emit ----
    for (int r = 0; r < 12; ++r) {
        unsigned long long key = keys[t + r * 256];
        if (key >= T) {
            unsigned pos = atomicAdd(&scnt, 1u);  // exactly 100 total
            sel[pos] = key;
        }
    }
    __syncthreads();
    if (t < KSEL) {
        unsigned long long key = sel[t];
        int rank = 0;
        for (int p = 0; p < KSEL; ++p) rank += (sel[p] > key) ? 1 : 0;
        unsigned idx = 0xFFFFFFFFu - (unsigned)(key & 0xFFFFFFFFull);
        float conf = __uint_as_float((unsigned)(key >> 32));
        int n = b * KSEL + rank;
        const float* pe = pb + (size_t)idx * 5;
        int w = idx & 31, h = (idx >> 5) & 31;  // flat = a*1024 + h*32 + w
        float x  = (sigf(pe[0]) + (float)w) * 32.0f;
        float y  = (sigf(pe[1]) + (float)h) * 32.0f;
        float bw = expf(pe[2]) * 32.0f;
        float bh = expf(pe[3]) * 32.0f;
        predc[n * 4 + 0] = x - bw * 0.5f;
        predc[n * 4 + 1] = y - bh * 0.5f;
        predc[n * 4 + 2] = x + bw * 0.5f;
        predc[n * 4 + 3] = y + bh * 0.5f;
        // u-histogram contribution
        float o = 1.0f - conf;
        float u = o * o;
        int bk = min((int)(u * HSCALE), HBUCK - 1);
        atomicAdd(&hcnt[bk], 1.0f);
        atomicAdd(&hsum[bk], u);
    }
    __syncthreads();
    if (t < HBUCK) {
        hist_g[t * 64 + b] = hcnt[t];
        hist_g[HBUCK * 64 + t * 64 + b] = hsum[t];
    }
}

// ---------------------------------------------------------------------------
// k_maxiou: grid (25, 50). Division-free running max (validated round 3):
// maximizing in/(S-in) == cross-compare "in*bs > bi*S" (in*bi terms cancel);
// rcp once per thread at the end.
// blockIdx.y == 0 additionally computes paired DIoU and the smooth-L1 partial.
// ---------------------------------------------------------------------------
__global__ __launch_bounds__(256) void k_maxiou(const float* __restrict__ predc,
                                                const float* __restrict__ targc,
                                                unsigned int* __restrict__ maxiou_bits,
                                                float* __restrict__ diouv,
                                                double* __restrict__ sl1p /*[25]*/) {
    __shared__ float4 pl[PCHUNK];
    __shared__ float pa_sh[PCHUNK];
    int t = threadIdx.x;
    int j = blockIdx.x * 256 + t;
    const float4* pc4 = (const float4*)predc;
    int i0 = blockIdx.y * PCHUNK;
    if (t < PCHUNK) {
        float4 p = pc4[i0 + t];
        pl[t] = p;
        pa_sh[t] = (p.z - p.x) * (p.w - p.y);
    }
    float4 tj = ((const float4*)targc)[j];
    float ta = (tj.z - tj.x) * (tj.w - tj.y);
    __syncthreads();
    // running best (intersection, pa+ta) pairs; init iou=0 as (0,1)
    float bi0 = 0.f, bs0 = 1.f, bi1 = 0.f, bs1 = 1.f;
    float bi2 = 0.f, bs2 = 1.f, bi3 = 0.f, bs3 = 1.f;
    #pragma unroll 2
    for (int i = 0; i < PCHUNK; i += 4) {
        {
            float4 p = pl[i];
            float w = fmaxf(fminf(p.z, tj.z) - fmaxf(p.x, tj.x), 0.0f);
            float h = fmaxf(fminf(p.w, tj.w) - fmaxf(p.y, tj.y), 0.0f);
            float in = w * h;
            float S = pa_sh[i] + ta;
            bool up = in * bs0 > bi0 * S;
            bi0 = up ? in : bi0; bs0 = up ? S : bs0;
        }
        {
            float4 p = pl[i + 1];
            float w = fmaxf(fminf(p.z, tj.z) - fmaxf(p.x, tj.x), 0.0f);
            float h = fmaxf(fminf(p.w, tj.w) - fmaxf(p.y, tj.y), 0.0f);
            float in = w * h;
            float S = pa_sh[i + 1] + ta;
            bool up = in * bs1 > bi1 * S;
            bi1 = up ? in : bi1; bs1 = up ? S : bs1;
        }
        {
            float4 p = pl[i + 2];
            float w = fmaxf(fminf(p.z, tj.z) - fmaxf(p.x, tj.x), 0.0f);
            float h = fmaxf(fminf(p.w, tj.w) - fmaxf(p.y, tj.y), 0.0f);
            float in = w * h;
            float S = pa_sh[i + 2] + ta;
            bool up = in * bs2 > bi2 * S;
            bi2 = up ? in : bi2; bs2 = up ? S : bs2;
        }
        {
            float4 p = pl[i + 3];
            float w = fmaxf(fminf(p.z, tj.z) - fmaxf(p.x, tj.x), 0.0f);
            float h = fmaxf(fminf(p.w, tj.w) - fmaxf(p.y, tj.y), 0.0f);
            float in = w * h;
            float S = pa_sh[i + 3] + ta;
            bool up = in * bs3 > bi3 * S;
            bi3 = up ? in : bi3; bs3 = up ? S : bs3;
        }
    }
    {
        bool u01 = bi1 * bs0 > bi0 * bs1;
        float ai = u01 ? bi1 : bi0, as = u01 ? bs1 : bs0;
        bool u23 = bi3 * bs2 > bi2 * bs3;
        float ci = u23 ? bi3 : bi2, cs = u23 ? bs3 : bs2;
        bool um = ci * as > ai * cs;
        float fi = um ? ci : ai, fs = um ? cs : as;
        float iou = fi * __builtin_amdgcn_rcpf(fs - fi);  // union > 0 (or 1 at init)
        atomicMax(&maxiou_bits[j], __float_as_uint(iou));
    }

    if (blockIdx.y == 0) {
        float4 p = pc4[j];  // paired pred for target j
        float pa = fmaxf(p.z - p.x, 0.f) * fmaxf(p.w - p.y, 0.f);
        float ta2 = fmaxf(tj.z - tj.x, 0.f) * fmaxf(tj.w - tj.y, 0.f);
        float ix1 = fmaxf(p.x, tj.x), iy1 = fmaxf(p.y, tj.y);
        float ix2 = fminf(p.z, tj.z), iy2 = fminf(p.w, tj.w);
        float inter = fmaxf(ix2 - ix1, 0.f) * fmaxf(iy2 - iy1, 0.f);
        float iou = inter / (pa + ta2 - inter + 1e-7f);
        float pcx = (p.x + p.z) * 0.5f, pcy = (p.y + p.w) * 0.5f;
        float tcx = (tj.x + tj.z) * 0.5f, tcy = (tj.y + tj.w) * 0.5f;
        float cd = (pcx - tcx) * (pcx - tcx) + (pcy - tcy) * (pcy - tcy);
        float ex1 = fminf(p.x, tj.x), ey1 = fminf(p.y, tj.y);
        float ex2 = fmaxf(p.z, tj.z), ey2 = fmaxf(p.w, tj.w);
        float dg = (ex2 - ex1) * (ex2 - ex1) + (ey2 - ey1) * (ey2 - ey1);
        diouv[j] = 1.0f - (iou - cd / (dg + 1e-7f));
        double s = 0.0;
        {
            float d0 = p.x - tj.x, d1 = p.y - tj.y, d2 = p.z - tj.z, d3 = p.w - tj.w;
            float a0 = fabsf(d0), a1 = fabsf(d1), a2 = fabsf(d2), a3 = fabsf(d3);
            s += (double)(a0 < 1.f ? 0.5f * d0 * d0 : a0 - 0.5f);
            s += (double)(a1 < 1.f ? 0.5f * d1 * d1 : a1 - 0.5f);
            s += (double)(a2 < 1.f ? 0.5f * d2 * d2 : a2 - 0.5f);
            s += (double)(a3 < 1.f ? 0.5f * d3 * d3 : a3 - 0.5f);
        }
        double v = block_reduce_sum(s);
        if (t == 0) sl1p[blockIdx.x] = v;
    }
}

// ---------------------------------------------------------------------------
// k_pair: histogram form. For each j:
//   sum_i sqrt(c + u_i) ~= sum_buckets cnt_b * sqrt(c + ubar_b)
// (2nd-order bucket error <= ~1e-5 on the final mean; bucket width 4.9e-4).
// Works for BOTH sides (c = x^2 and c = (3.5-x)^2) at any x -- no series,
// no fallback. Grid (25 j-chunks, 4 bucket-slices) x 256; thread = one j,
// HSLICE=32 bucket iterations in f64 accumulation.
// ---------------------------------------------------------------------------
__global__ __launch_bounds__(256) void k_pair(const unsigned int* __restrict__ maxiou_bits,
                                              const float* __restrict__ diouv,
                                              const double* __restrict__ sl1p /*[25]*/,
                                              const float* __restrict__ hist_g /*[2][128][64]*/,
                                              double* __restrict__ pairp /*[100]*/) {
    __shared__ float2 hb[HSLICE];   // (cnt, ubar) per bucket in this slice
    int t = threadIdx.x;
    int lane = t & 63;
    int j = blockIdx.x * 256 + t;
    int k0 = blockIdx.y * HSLICE;

    float sl1;
    {
        double a = (lane < 25) ? sl1p[lane] : 0.0;
        for (int off = 32; off; off >>= 1) a += __shfl_xor(a, off, 64);
        sl1 = (float)(a / 25600.0 / 512.0);
    }
    if (t < HSLICE) {
        const float* pc = hist_g + (size_t)(k0 + t) * 64;
        const float* ps = hist_g + HBUCK * 64 + (size_t)(k0 + t) * 64;
        float cn = 0.0f, su = 0.0f;
        for (int b = 0; b < 64; ++b) { cn += pc[b]; su += ps[b]; }
        float ub = (cn > 0.0f) ? su / cn : 0.0f;
        hb[t] = make_float2(cn, ub);
    }
    float mj = __uint_as_float(maxiou_bits[j]);
    float dj = diouv[j];
    __syncthreads();
    float xj = (1.0f - mj) * 2.0f + dj + sl1;
    float bb = 3.5f - xj;
    float b2 = bb * bb;
    float x2 = xj * xj;
    double gacc = 0.0, bacc = 0.0;
    #pragma unroll 8
    for (int k = 0; k < HSLICE; ++k) {
        float2 h = hb[k];
        gacc += (double)(h.x * __builtin_amdgcn_sqrtf(x2 + h.y));
        bacc += (double)(h.x * __builtin_amdgcn_sqrtf(b2 + h.y));
    }
    double v = 2.0 * gacc - 1.5 * bacc;
    double r = block_reduce_sum(v);
    if (t == 0) pairp[blockIdx.x * 4 + blockIdx.y] = r;
}

// ---------------------------------------------------------------------------
// k_final: reduce 100 pair partials + 64 negpen partials, emit scalar.
// ---------------------------------------------------------------------------
__global__ __launch_bounds__(256) void k_final(const double* __restrict__ pairp,
                                               const double* __restrict__ negp,
                                               float* __restrict__ out) {
    int t = threadIdx.x;
    double s = (t < NPAIRBLK) ? pairp[t] : 0.0;
    double ps = block_reduce_sum(s);
    double n = (t < 64) ? negp[t] : 0.0;
    double ns = block_reduce_sum(n);
    if (t == 0) {
        double mean_pair = ps / 40960000.0;                    // 6400*6400
        float losses = fmaxf((float)mean_pair + 5.25f, 0.0f);  // + 3.5*1.5
        float neg = (float)(ns / 196608.0);
        out[0] = losses + neg;
    }
}

// ---------------- launch ----------------

extern "C" void kernel_launch(void* const* d_in, const int* in_sizes, int n_in,
                              void* d_out, int out_size, void* d_ws, size_t ws_size,
                              hipStream_t stream) {
    const float* pred = (const float*)d_in[0];   // [64,3,32,32,5]
    const float* tgt  = (const float*)d_in[1];   // [64,100,4]
    float* out = (float*)d_out;

    char* ws = (char*)d_ws;
    double* negp  = (double*)ws;             // 64 doubles
    double* sl1p  = negp + 64;               // 25 (pad to 32)
    double* pairp = negp + 96;               // 100 -> ends at 196*8 = 1568
    float* hist_g = (float*)(ws + 2048);     // 2*128*64 floats = 64 KB
    float* fbase  = (float*)(ws + 2048 + 65536);
    float* predc  = fbase;                   // 25600 floats
    float* targc  = fbase + 25600;           // 25600
    float* diouv  = fbase + 51200;           // 6400
    unsigned int* maxiou_bits = (unsigned int*)(fbase + 57600);  // 6400

    k_topk<<<64, 256, 0, stream>>>(pred, tgt, predc, targc, maxiou_bits,
                                   negp, hist_g);
    k_maxiou<<<dim3(25, 6400 / PCHUNK), 256, 0, stream>>>(predc, targc, maxiou_bits,
                                                          diouv, sl1p);
    k_pair<<<dim3(25, 4), 256, 0, stream>>>(maxiou_bits, diouv, sl1p, hist_g, pairp);
    k_final<<<1, 256, 0, stream>>>(pairp, negp, out);
}